// Round 10
// baseline (305.510 us; speedup 1.0000x reference)
//
#include <hip/hip_runtime.h>
#include <hip/hip_bf16.h>
#include <math.h>

#define B_SZ 256
#define F_SZ 2048
#define C_SZ 16384
#define P_SZ 8
#define N_SZ 32
#define NTILE 256   // C_SZ / BN softmax partials per row

typedef __bf16 bf16x8 __attribute__((ext_vector_type(8)));
typedef float f32x4 __attribute__((ext_vector_type(4)));
typedef unsigned short us8 __attribute__((ext_vector_type(8)));

typedef __attribute__((address_space(3))) unsigned int lds_u32;
typedef __attribute__((address_space(1))) const unsigned int glb_u32;

// s_waitcnt immediates (gfx9 encoding): vm[3:0],[15:14]; exp[6:4]; lgkm[11:8]
#define WAITCNT_VM6   0x0F76   // vmcnt(6), exp/lgkm ignored
#define WAITCNT_VM0   0x0F70   // vmcnt(0), exp/lgkm ignored

__device__ __forceinline__ unsigned short f2bf(float x) {
    union { float f; unsigned int u; } v; v.f = x;
    unsigned int r = v.u + 0x7FFFu + ((v.u >> 16) & 1u);  // RTN-even
    return (unsigned short)(r >> 16);
}

// ---------------- kernel 1: row norms + bf16 cast of inputs ----------------
__global__ __launch_bounds__(256) void prep_kernel(const float* __restrict__ inputs,
                                                   unsigned short* __restrict__ Abf,
                                                   float* __restrict__ norms) {
    const int row = blockIdx.x;
    const int tid = threadIdx.x;
    const float* rp = inputs + (size_t)row * F_SZ + tid * 8;
    float4 v0 = *(const float4*)(rp);
    float4 v1 = *(const float4*)(rp + 4);
    us8 o;
    o[0]=f2bf(v0.x); o[1]=f2bf(v0.y); o[2]=f2bf(v0.z); o[3]=f2bf(v0.w);
    o[4]=f2bf(v1.x); o[5]=f2bf(v1.y); o[6]=f2bf(v1.z); o[7]=f2bf(v1.w);
    *(us8*)(Abf + (size_t)row * F_SZ + tid * 8) = o;
    float ss = v0.x*v0.x + v0.y*v0.y + v0.z*v0.z + v0.w*v0.w
             + v1.x*v1.x + v1.y*v1.y + v1.z*v1.z + v1.w*v1.w;
    __shared__ float red[256];
    red[tid] = ss; __syncthreads();
    for (int s = 128; s > 0; s >>= 1) { if (tid < s) red[tid] += red[tid+s]; __syncthreads(); }
    if (tid == 0) norms[row] = sqrtf(red[0]);
}

// ---------------- kernel 2: outputs = inputs @ V^T ----------------
// BM=256 (full M), BN=64, BK=64, 512 thr (8 waves as 4m x 2n; wave tile
// 64x32). Grid = 256 = 1 block/CU; V streamed from HBM/L3 exactly once.
// BOTH operands staged via global_load_lds into 3-deep rings issued 2 tiles
// ahead: A bf16 (XOR-swizzled by row&7), B *fp32* (XOR-swizzled 16B chunks
// by col&15) converted to bf16 at consume time in registers. The K-loop has
// NO ds_writes and NO lgkm drain: {6 glds, 16 ds_read, cvt, 16 MFMA,
// vmcnt(6), raw s_barrier} per iteration; tile it+2's 6 loads stay in
// flight across the barrier. LDS = 96 + 48 + 4 = 148 KB.
#define BM 256
#define BN 64
#define BK 64
#define KITERS (F_SZ / BK)   // 32

__global__ __launch_bounds__(512, 1) void gemm_kernel(const unsigned short* __restrict__ Abf,
                                                      const float* __restrict__ V,
                                                      float* __restrict__ Cout,
                                                      float* __restrict__ pmax,
                                                      float* __restrict__ psum) {
    __shared__ unsigned short As[3][BM * BK];    // 3 x 32 KB ring (bf16)
    __shared__ float Bs[3][BN * BK];             // 3 x 16 KB ring (fp32)
    __shared__ float sm[BM * 2], ss2[BM * 2];

    const int tid = threadIdx.x;
    const int lane = tid & 63;
    const int wid = tid >> 6;                    // 0..7
    const int wm = wid >> 1, wn = wid & 1;       // 4 m-waves x 2 n-waves
    const int q = lane >> 4, l16 = lane & 15;

    const int slab = blockIdx.x;                 // 0..255, disjoint V slabs
    const int bn0 = slab * BN;

    f32x4 acc[4][2];
    #pragma unroll
    for (int i = 0; i < 4; i++)
        #pragma unroll
        for (int j = 0; j < 2; j++) acc[i][j] = (f32x4){0.f, 0.f, 0.f, 0.f};

    // ---- A staging map: issue j covers rows [j*64, j*64+64);
    //      thread t: row = j*64 + (t>>3); slot chunk c = t&7 holds global
    //      chunk kc = c ^ (row&7); LDS slot = (j*512 + t)*16B.
    const int arow = tid >> 3;                   // 0..63
    const int akc = (tid & 7) ^ (arow & 7);
    const unsigned short* AgBase = Abf + (size_t)arow * F_SZ + akc * 8;

    // ---- B staging map (fp32, row = 256B = 16 chunks of 16B):
    //      issue j covers rows [j*32, j*32+32); thread t: row = j*32 + (t>>4),
    //      slot chunk c = t&15 holds global chunk kc = c ^ (row&15);
    //      LDS slot = (j*512 + t)*16B.
    const int brow = tid >> 4;                   // 0..31
    const int bkc = (tid & 15) ^ (brow & 15);
    const float* BgBase = V + (size_t)(bn0 + brow) * F_SZ + bkc * 4;

    auto issueTile = [&](int ring, int k0) {
        #pragma unroll
        for (int j = 0; j < 4; ++j) {            // A: 256 rows = 4 issues
            __builtin_amdgcn_global_load_lds(
                (glb_u32*)(AgBase + (size_t)j * 64 * F_SZ + k0),
                (lds_u32*)&As[ring][(j * 512 + tid) * 8],
                16, 0, 0);
        }
        #pragma unroll
        for (int j = 0; j < 2; ++j) {            // B: 64 rows = 2 issues
            __builtin_amdgcn_global_load_lds(
                (glb_u32*)(BgBase + (size_t)j * 32 * F_SZ + k0),
                (lds_u32*)&Bs[ring][(j * 512 + tid) * 4],
                16, 0, 0);
        }
    };
    auto compute = [&](int ring) {
        #pragma unroll
        for (int ks = 0; ks < 2; ++ks) {
            bf16x8 af[4], bfv[2];
            const int kc = ks * 4 + q;           // A chunk index (8 bf16 = 16B)
            #pragma unroll
            for (int mi = 0; mi < 4; ++mi) {
                const int row = wm * 64 + mi * 16 + l16;
                af[mi] = *(const bf16x8*)&As[ring][row * 64 + (kc ^ (row & 7)) * 8];
            }
            #pragma unroll
            for (int ni = 0; ni < 2; ++ni) {
                const int col = wn * 32 + ni * 16 + l16;
                // need floats [ks*32 + q*8 .. +8) = fp32 chunks kca, kca+1
                const int kca = ks * 8 + q * 2;
                const int sa = kca ^ (col & 15);
                const int sb = (kca + 1) ^ (col & 15);
                f32x4 va = *(const f32x4*)&Bs[ring][col * 64 + sa * 4];
                f32x4 vb = *(const f32x4*)&Bs[ring][col * 64 + sb * 4];
                us8 w;
                w[0]=f2bf(va[0]); w[1]=f2bf(va[1]); w[2]=f2bf(va[2]); w[3]=f2bf(va[3]);
                w[4]=f2bf(vb[0]); w[5]=f2bf(vb[1]); w[6]=f2bf(vb[2]); w[7]=f2bf(vb[3]);
                bfv[ni] = __builtin_bit_cast(bf16x8, w);
            }
            #pragma unroll
            for (int mi = 0; mi < 4; ++mi)
                #pragma unroll
                for (int ni = 0; ni < 2; ++ni)
                    acc[mi][ni] = __builtin_amdgcn_mfma_f32_16x16x32_bf16(af[mi], bfv[ni], acc[mi][ni], 0, 0, 0);
        }
    };

    // prologue: tile0 -> ring0, tile1 -> ring1; drain tile0 only (6 newest stay)
    issueTile(0, 0);       // 6 vm
    issueTile(1, BK);      // 6 vm -> 12 outstanding
    __builtin_amdgcn_s_waitcnt(WAITCNT_VM6);   // tile0 done; tile1 in flight
    __builtin_amdgcn_s_barrier();

    int cur = 0;                        // it % 3
    int nxt2 = 2;                       // (it+2) % 3
    #pragma unroll 1
    for (int it = 0; it < KITERS; ++it) {
        // invariant at top: outstanding = tile(it+1) [6 vm]
        if (it + 2 < KITERS) issueTile(nxt2, (it + 2) * BK);   // +6 vm
        compute(cur);
        // drain tile it+1 (oldest 6); keep tile it+2 (newest 6) in flight
        if (it + 2 < KITERS)      __builtin_amdgcn_s_waitcnt(WAITCNT_VM6);
        else if (it + 1 < KITERS) __builtin_amdgcn_s_waitcnt(WAITCNT_VM0);
        if (it + 1 < KITERS) __builtin_amdgcn_s_barrier();     // raw: no lgkm, no full drain
        cur  = (cur == 2) ? 0 : cur + 1;
        nxt2 = (nxt2 == 2) ? 0 : nxt2 + 1;
    }

    // epilogue: D row=(lane>>4)*4+reg, col=lane&15  [verified m89/m91]
    #pragma unroll
    for (int mi = 0; mi < 4; ++mi) {
        const int r0 = wm * 64 + mi * 16 + q * 4;
        #pragma unroll
        for (int ni = 0; ni < 2; ++ni) {
            const int c0 = bn0 + wn * 32 + ni * 16 + l16;
            #pragma unroll
            for (int r = 0; r < 4; ++r)
                Cout[(size_t)(r0 + r) * C_SZ + c0] = acc[mi][ni][r];
        }
    }

    // fused partial softmax over this block's 64 cols (per wave: 32 cols)
    #pragma unroll
    for (int mi = 0; mi < 4; ++mi) {
        #pragma unroll
        for (int r = 0; r < 4; ++r) {
            float mloc = fmaxf(acc[mi][0][r], acc[mi][1][r]);
            #pragma unroll
            for (int off = 1; off < 16; off <<= 1)
                mloc = fmaxf(mloc, __shfl_xor(mloc, off, 64));
            float sloc = __expf(acc[mi][0][r] - mloc) + __expf(acc[mi][1][r] - mloc);
            #pragma unroll
            for (int off = 1; off < 16; off <<= 1)
                sloc += __shfl_xor(sloc, off, 64);
            if (l16 == 0) {
                const int lrow = wm * 64 + mi * 16 + q * 4 + r;
                sm[lrow * 2 + wn] = mloc;
                ss2[lrow * 2 + wn] = sloc;
            }
        }
    }
    __syncthreads();
    if (tid < BM) {
        float m1 = sm[tid * 2], s1 = ss2[tid * 2];
        float m2 = sm[tid * 2 + 1], s2 = ss2[tid * 2 + 1];
        float nm = fmaxf(m1, m2);
        float s = s1 * __expf(m1 - nm) + s2 * __expf(m2 - nm);
        pmax[tid * NTILE + slab] = nm;
        psum[tid * NTILE + slab] = s;
    }
}

// ------- kernel 3: softmax-combine (fused) + pair matching + sims + hard-pair sums -------
__global__ __launch_bounds__(256) void pairs_kernel(
    const float* __restrict__ inputs, const int* __restrict__ targets,
    const int* __restrict__ ppairs, const int* __restrict__ npairs,
    const int* __restrict__ indexs, const int* __restrict__ cluster,
    const float* __restrict__ outputs, const float* __restrict__ norms,
    const float* __restrict__ pmax, const float* __restrict__ psum,
    float* __restrict__ bu_part,
    float* __restrict__ hp_part, float* __restrict__ hn_part,
    int* __restrict__ flag_part)
{
    const int i = blockIdx.x;
    const int tid = threadIdx.x;
    __shared__ int idxbuf[B_SZ];
    __shared__ int pj[P_SZ];
    __shared__ int nj[N_SZ];
    __shared__ float simp[P_SZ];
    __shared__ float simn[N_SZ];
    __shared__ float tnv[N_SZ];
    __shared__ float s_tp;
    __shared__ float rm[256], rs[256];

    idxbuf[tid] = indexs[tid];
    // softmax combine for row i (NTILE=256 partials)
    rm[tid] = pmax[i * NTILE + tid];
    rs[tid] = psum[i * NTILE + tid];
    __syncthreads();
    for (int s = 128; s > 0; s >>= 1) {
        if (tid < s) {
            float a = rm[tid], sa = rs[tid];
            float b = rm[tid + s], sb = rs[tid + s];
            float nn = fmaxf(a, b);
            rs[tid] = sa * __expf(a - nn) + sb * __expf(b - nn);
            rm[tid] = nn;
        }
        __syncthreads();
    }

    const float* row = outputs + (size_t)i * C_SZ;
    const float ni_norm = norms[i];

    if (tid == 0) {
        float logZ = rm[0] + logf(rs[0]);
        bu_part[i] = -(row[targets[i]] - logZ);
    }

    // pair matching (indexs is a permutation -> at most one match; argmax = first)
    if (tid < P_SZ) {
        int pp = ppairs[i * P_SZ + tid];
        int f = -1;
        if (pp >= 0) for (int j = 0; j < B_SZ; j++) if (idxbuf[j] == pp) { f = j; break; }
        pj[tid] = f;
    } else if (tid < P_SZ + N_SZ) {
        int t = tid - P_SZ;
        int np = npairs[i * N_SZ + t];
        int f = -1;
        if (np >= 0) for (int j = 0; j < B_SZ; j++) if (idxbuf[j] == np) { f = j; break; }
        nj[t] = f;
        int cid = cluster[np < 0 ? 0 : np];           // jnp.clip(npairs, 0)
        tnv[t] = row[cid] / ni_norm;                  // tsims[i, ncid] = outputs/norm
    }
    if (tid == P_SZ + N_SZ) s_tp = row[targets[i]] / ni_norm;
    __syncthreads();

    // in-batch sims (fp32, exact semantics incl. self-match ~1.0): one pair per wave round-robin
    const int lane = tid & 63, wv = tid >> 6;
    for (int qq = wv; qq < P_SZ + N_SZ; qq += 4) {
        int j = (qq < P_SZ) ? pj[qq] : nj[qq - P_SZ];
        float s = 0.f;
        if (j >= 0) {
            const float* xi = inputs + (size_t)i * F_SZ;
            const float* xj = inputs + (size_t)j * F_SZ;
            float d = 0.f;
            for (int k = lane; k < F_SZ; k += 64) d += xi[k] * xj[k];
            for (int off = 32; off > 0; off >>= 1) d += __shfl_down(d, off);
            s = d / (ni_norm * norms[j]);
        }
        if (lane == 0) { if (qq < P_SZ) simp[qq] = s; else simn[qq - P_SZ] = s; }
    }
    __syncthreads();

    if (tid == 0) {
        float psims[P_SZ + 1]; bool pmask[P_SZ + 1];
        for (int p = 0; p < P_SZ; p++) {
            int pp = ppairs[i * P_SZ + p];
            pmask[p] = (pj[p] >= 0) && (pp >= 0);
            psims[p] = simp[p];
        }
        psims[P_SZ] = s_tp; pmask[P_SZ] = (s_tp != 0.0f);

        float nsims[2 * N_SZ]; bool nmask[2 * N_SZ];
        for (int t = 0; t < N_SZ; t++) {
            int np = npairs[i * N_SZ + t];
            nmask[t] = (nj[t] >= 0) && (np >= 0);
            nsims[t] = simn[t];
            nsims[N_SZ + t] = tnv[t];
            nmask[N_SZ + t] = (np >= 0) && (tnv[t] != 0.0f);
        }
        bool anyp = false, anyn = false;
        float maxn = -INFINITY, minp = INFINITY;
        for (int t = 0; t < 2 * N_SZ; t++) if (nmask[t]) { anyn = true; maxn = fmaxf(maxn, nsims[t]); }
        for (int p = 0; p < P_SZ + 1; p++) if (pmask[p]) { anyp = true; minp = fminf(minp, psims[p]); }
        float p_thrd = (anyn ? maxn : -3.0f) + 0.1f;
        float n_thrd = (anyp ? minp : 3.0f) - 0.1f;
        float hps = 0.f, hns = 0.f; int fl = 0;
        for (int p = 0; p < P_SZ + 1; p++)
            if (pmask[p] && psims[p] < p_thrd) { fl |= 1; hps += expf(-2.0f * (psims[p] - 0.5f)); }
        for (int t = 0; t < 2 * N_SZ; t++)
            if (nmask[t] && nsims[t] > n_thrd && nsims[t] < 0.999999f) { fl |= 2; hns += expf(50.0f * (nsims[t] - 0.5f)); }
        hp_part[i] = hps; hn_part[i] = hns; flag_part[i] = fl;
    }
}

// ---------------- kernel 4: final scalar reduce ----------------
__global__ __launch_bounds__(256) void finalize_kernel(
    const float* __restrict__ bu_part, const float* __restrict__ hp_part,
    const float* __restrict__ hn_part, const int* __restrict__ flag_part,
    float* __restrict__ d_out)
{
    __shared__ float r1[256], r2[256], r3[256];
    __shared__ int rf[256];
    const int tid = threadIdx.x;
    r1[tid] = bu_part[tid]; r2[tid] = hp_part[tid]; r3[tid] = hn_part[tid]; rf[tid] = flag_part[tid];
    __syncthreads();
    for (int s = 128; s > 0; s >>= 1) {
        if (tid < s) { r1[tid] += r1[tid+s]; r2[tid] += r2[tid+s]; r3[tid] += r3[tid+s]; rf[tid] |= rf[tid+s]; }
        __syncthreads();
    }
    if (tid == 0) {
        float bu = r1[0] / (float)B_SZ;
        float hp_loss = (rf[0] & 1) ? 0.5f * log1pf(r2[0]) : 0.0f;
        float hn_loss = (rf[0] & 2) ? (1.0f / 50.0f) * log1pf(r3[0]) : 0.0f;
        d_out[0] = 1.0f * bu + 10.0f * (hp_loss + hn_loss);   // W_BU=1, W_H=10
    }
}

extern "C" void kernel_launch(void* const* d_in, const int* in_sizes, int n_in,
                              void* d_out, int out_size, void* d_ws, size_t ws_size,
                              hipStream_t stream) {
    const float* inputs  = (const float*)d_in[0];
    const int*   targets = (const int*)d_in[1];
    const int*   ppairs  = (const int*)d_in[2];
    const int*   npairs  = (const int*)d_in[3];
    const int*   indexs  = (const int*)d_in[4];
    const int*   cluster = (const int*)d_in[5];
    const float* V       = (const float*)d_in[6];
    float* out = (float*)d_out;           // [0] = loss, [1..] = outputs row-major [B][C]

    char* ws = (char*)d_ws;
    unsigned short* Abf = (unsigned short*)ws;                       // 1 MB
    float* norms   = (float*)(ws + (size_t)B_SZ * F_SZ * 2);
    float* bu_part = norms + B_SZ;
    float* hp_part = bu_part + B_SZ;
    float* hn_part = hp_part + B_SZ;
    int*   flag_part = (int*)(hn_part + B_SZ);
    float* pmax = (float*)(flag_part + B_SZ);                        // 256 KB
    float* psum = pmax + (size_t)B_SZ * NTILE;                       // 256 KB

    prep_kernel<<<B_SZ, 256, 0, stream>>>(inputs, Abf, norms);
    gemm_kernel<<<256, 512, 0, stream>>>(Abf, V, out + 1, pmax, psum);
    pairs_kernel<<<B_SZ, 256, 0, stream>>>(inputs, targets, ppairs, npairs, indexs,
                                           cluster, out + 1, norms, pmax, psum,
                                           bu_part, hp_part, hn_part, flag_part);
    finalize_kernel<<<1, 256, 0, stream>>>(bu_part, hp_part, hn_part, flag_part, out);
}

// Round 12
// 301.014 us; speedup vs baseline: 1.0149x; 1.0149x over previous
//
#include <hip/hip_runtime.h>
#include <hip/hip_bf16.h>
#include <math.h>

#define B_SZ 256
#define F_SZ 2048
#define C_SZ 16384
#define P_SZ 8
#define N_SZ 32
#define NTILE 256   // C_SZ / BN softmax partials per row

typedef __bf16 bf16x8 __attribute__((ext_vector_type(8)));
typedef float f32x4 __attribute__((ext_vector_type(4)));
typedef unsigned short us8 __attribute__((ext_vector_type(8)));

typedef __attribute__((address_space(3))) unsigned int lds_u32;
typedef __attribute__((address_space(1))) const unsigned int glb_u32;

// s_waitcnt immediates (gfx9 encoding): vm[3:0],[15:14]; exp[6:4]; lgkm[11:8]
#define WAITCNT_VM4   0x0F74   // vmcnt(4), exp/lgkm ignored
#define WAITCNT_VM0   0x0F70   // vmcnt(0), exp/lgkm ignored
#define WAITCNT_LGKM0 0xC07F   // lgkmcnt(0), vm/exp ignored

__device__ __forceinline__ unsigned short f2bf(float x) {
    union { float f; unsigned int u; } v; v.f = x;
    unsigned int r = v.u + 0x7FFFu + ((v.u >> 16) & 1u);  // RTN-even
    return (unsigned short)(r >> 16);
}

// ---------------- kernel 1: row norms + bf16 cast of inputs ----------------
__global__ __launch_bounds__(256) void prep_kernel(const float* __restrict__ inputs,
                                                   unsigned short* __restrict__ Abf,
                                                   float* __restrict__ norms) {
    const int row = blockIdx.x;
    const int tid = threadIdx.x;
    const float* rp = inputs + (size_t)row * F_SZ + tid * 8;
    float4 v0 = *(const float4*)(rp);
    float4 v1 = *(const float4*)(rp + 4);
    us8 o;
    o[0]=f2bf(v0.x); o[1]=f2bf(v0.y); o[2]=f2bf(v0.z); o[3]=f2bf(v0.w);
    o[4]=f2bf(v1.x); o[5]=f2bf(v1.y); o[6]=f2bf(v1.z); o[7]=f2bf(v1.w);
    *(us8*)(Abf + (size_t)row * F_SZ + tid * 8) = o;
    float ss = v0.x*v0.x + v0.y*v0.y + v0.z*v0.z + v0.w*v0.w
             + v1.x*v1.x + v1.y*v1.y + v1.z*v1.z + v1.w*v1.w;
    __shared__ float red[256];
    red[tid] = ss; __syncthreads();
    for (int s = 128; s > 0; s >>= 1) { if (tid < s) red[tid] += red[tid+s]; __syncthreads(); }
    if (tid == 0) norms[row] = sqrtf(red[0]);
}

// ---------------- kernel 2: outputs = inputs @ V^T ----------------
// BM=256 (FULL M per block), BN=64, BK=64, 512 thr (8 waves as 4m x 2n;
// wave tile 64x32). Grid = 256 = C/BN = 1 block/CU: flow-optimal tiling
// (total staged flow = 256 x 2048 x (2*256 + 4*64) ~= 400 MB, the minimum
// over grid>=256 tilings; per-CU floor ~63-65 us at the measured ~10 B/cyc
// VMEM staging rate). V streamed fp32 from HBM/L3 exactly once per slab.
// Schedule (measured best, R9 = 80 us): A 3-deep global_load_lds ring
// issued 2 tiles ahead; B fp32 -> single reg set -> bf16 (converted ONCE at
// stage time) -> LDS dbuf issued 1 ahead; counted vmcnt(4) keeps A(it+2)
// in flight across a raw s_barrier. In-loop VALU kept off the consume path
// (R10's consume-time cvt variant: +8pp VALUBusy, +9 us — reverted).
#define BM 256
#define BN 64
#define BK 64
#define BPAD 72
#define KITERS (F_SZ / BK)   // 32

__global__ __launch_bounds__(512, 1) void gemm_kernel(const unsigned short* __restrict__ Abf,
                                                      const float* __restrict__ V,
                                                      float* __restrict__ Cout,
                                                      float* __restrict__ pmax,
                                                      float* __restrict__ psum) {
    __shared__ unsigned short As[3][BM * BK];    // 3 x 32 KB ring, swizzled
    __shared__ unsigned short Bs[2][BN * BPAD];  // 2 x 9 KB, padded
    __shared__ float sm[BM * 2], ss2[BM * 2];

    const int tid = threadIdx.x;
    const int lane = tid & 63;
    const int wid = tid >> 6;                    // 0..7
    const int wm = wid >> 1, wn = wid & 1;       // 4 m-waves x 2 n-waves
    const int q = lane >> 4, l16 = lane & 15;

    const int slab = blockIdx.x;                 // 0..255, disjoint V slabs
    const int bn0 = slab * BN;

    f32x4 acc[4][2];
    #pragma unroll
    for (int i = 0; i < 4; i++)
        #pragma unroll
        for (int j = 0; j < 2; j++) acc[i][j] = (f32x4){0.f, 0.f, 0.f, 0.f};

    // ---- A staging map: issue j covers rows [j*64, j*64+64);
    //      thread t: row = j*64 + (t>>3); stored chunk c = t&7 holds global
    //      chunk kc = c ^ (row&7); LDS slot = (j*512 + t)*16B.
    const int srow = tid >> 3;                   // 0..63
    const int skc = (tid & 7) ^ (srow & 7);
    const unsigned short* AgBase = Abf + (size_t)srow * F_SZ + skc * 8;

    // ---- B staging: thread -> (col = t>>3, kseg = t&7), 8 fp32 each
    const int bcol = tid >> 3, bseg = tid & 7;
    const float* BgBase = V + (size_t)(bn0 + bcol) * F_SZ + bseg * 8;
    const int bsoff = bcol * BPAD + bseg * 8;

    float4 b0, b1;   // single B reg set (two-set variant is schedule-unstable, R1)

    auto issueA = [&](int ring, int k0) {
        #pragma unroll
        for (int j = 0; j < 4; ++j) {            // 256 rows = 4 issues
            __builtin_amdgcn_global_load_lds(
                (glb_u32*)(AgBase + (size_t)j * 64 * F_SZ + k0),
                (lds_u32*)&As[ring][(j * 512 + tid) * 8],
                16, 0, 0);
        }
    };
    auto loadB = [&](int k0) {
        b0 = *(const float4*)(BgBase + k0);
        b1 = *(const float4*)(BgBase + k0 + 4);
    };
    auto writeB = [&](int buf) {
        us8 w;
        w[0]=f2bf(b0.x); w[1]=f2bf(b0.y); w[2]=f2bf(b0.z); w[3]=f2bf(b0.w);
        w[4]=f2bf(b1.x); w[5]=f2bf(b1.y); w[6]=f2bf(b1.z); w[7]=f2bf(b1.w);
        *(us8*)&Bs[buf][bsoff] = w;
    };
    auto compute = [&](int ring, int buf) {
        #pragma unroll
        for (int ks = 0; ks < 2; ++ks) {
            bf16x8 af[4], bfv[2];
            const int kc = ks * 4 + q;
            #pragma unroll
            for (int mi = 0; mi < 4; ++mi) {
                const int row = wm * 64 + mi * 16 + l16;
                af[mi] = *(const bf16x8*)&As[ring][row * 64 + (kc ^ (row & 7)) * 8];
            }
            #pragma unroll
            for (int ni = 0; ni < 2; ++ni) {
                const int col = wn * 32 + ni * 16 + l16;
                bfv[ni] = *(const bf16x8*)&Bs[buf][col * BPAD + ks * 32 + q * 8];
            }
            #pragma unroll
            for (int mi = 0; mi < 4; ++mi)
                #pragma unroll
                for (int ni = 0; ni < 2; ++ni)
                    acc[mi][ni] = __builtin_amdgcn_mfma_f32_16x16x32_bf16(af[mi], bfv[ni], acc[mi][ni], 0, 0, 0);
        }
    };

    // prologue: A(0)->ring0, B(0)->regs, A(1)->ring1
    issueA(0, 0);          // 4 vm
    loadB(0);              // 2 vm
    issueA(1, BK);         // 4 vm  -> 10 outstanding
    __builtin_amdgcn_s_waitcnt(WAITCNT_VM4);   // drain A(0)+B(0); keep A(1)
    writeB(0);
    __builtin_amdgcn_s_waitcnt(WAITCNT_LGKM0);
    __builtin_amdgcn_s_barrier();

    int cur = 0;                        // it % 3
    int nxt2 = 2;                       // (it+2) % 3
    #pragma unroll 1
    for (int it = 0; it < KITERS; ++it) {
        // invariant at top: outstanding = A(it+1) [4 vm]
        if (it + 1 < KITERS) loadB((it + 1) * BK);          // +2 vm
        if (it + 2 < KITERS) issueA(nxt2, (it + 2) * BK);   // +4 vm
        compute(cur, it & 1);
        // drain A(it+1)+B(it+1) (oldest 6); keep A(it+2) (newest 4)
        if (it + 2 < KITERS)      __builtin_amdgcn_s_waitcnt(WAITCNT_VM4);
        else if (it + 1 < KITERS) __builtin_amdgcn_s_waitcnt(WAITCNT_VM0);
        if (it + 1 < KITERS) {
            writeB((it + 1) & 1);
            __builtin_amdgcn_s_waitcnt(WAITCNT_LGKM0);  // ds_writes visible
            __builtin_amdgcn_s_barrier();               // raw: A(it+2) stays in flight
        }
        cur  = (cur == 2) ? 0 : cur + 1;
        nxt2 = (nxt2 == 2) ? 0 : nxt2 + 1;
    }

    // epilogue: D row=(lane>>4)*4+reg, col=lane&15  [verified m89/m91]
    #pragma unroll
    for (int mi = 0; mi < 4; ++mi) {
        const int r0 = wm * 64 + mi * 16 + q * 4;
        #pragma unroll
        for (int ni = 0; ni < 2; ++ni) {
            const int c0 = bn0 + wn * 32 + ni * 16 + l16;
            #pragma unroll
            for (int r = 0; r < 4; ++r)
                Cout[(size_t)(r0 + r) * C_SZ + c0] = acc[mi][ni][r];
        }
    }

    // fused partial softmax over this block's 64 cols (per wave: 32 cols)
    #pragma unroll
    for (int mi = 0; mi < 4; ++mi) {
        #pragma unroll
        for (int r = 0; r < 4; ++r) {
            float mloc = fmaxf(acc[mi][0][r], acc[mi][1][r]);
            #pragma unroll
            for (int off = 1; off < 16; off <<= 1)
                mloc = fmaxf(mloc, __shfl_xor(mloc, off, 64));
            float sloc = __expf(acc[mi][0][r] - mloc) + __expf(acc[mi][1][r] - mloc);
            #pragma unroll
            for (int off = 1; off < 16; off <<= 1)
                sloc += __shfl_xor(sloc, off, 64);
            if (l16 == 0) {
                const int lrow = wm * 64 + mi * 16 + q * 4 + r;
                sm[lrow * 2 + wn] = mloc;
                ss2[lrow * 2 + wn] = sloc;
            }
        }
    }
    __syncthreads();
    if (tid < BM) {
        float m1 = sm[tid * 2], s1 = ss2[tid * 2];
        float m2 = sm[tid * 2 + 1], s2 = ss2[tid * 2 + 1];
        float nm = fmaxf(m1, m2);
        float s = s1 * __expf(m1 - nm) + s2 * __expf(m2 - nm);
        pmax[tid * NTILE + slab] = nm;
        psum[tid * NTILE + slab] = s;
    }
}

// ------- kernel 3: softmax-combine (fused) + pair matching + sims + hard-pair sums -------
__global__ __launch_bounds__(256) void pairs_kernel(
    const float* __restrict__ inputs, const int* __restrict__ targets,
    const int* __restrict__ ppairs, const int* __restrict__ npairs,
    const int* __restrict__ indexs, const int* __restrict__ cluster,
    const float* __restrict__ outputs, const float* __restrict__ norms,
    const float* __restrict__ pmax, const float* __restrict__ psum,
    float* __restrict__ bu_part,
    float* __restrict__ hp_part, float* __restrict__ hn_part,
    int* __restrict__ flag_part)
{
    const int i = blockIdx.x;
    const int tid = threadIdx.x;
    __shared__ int idxbuf[B_SZ];
    __shared__ int pj[P_SZ];
    __shared__ int nj[N_SZ];
    __shared__ float simp[P_SZ];
    __shared__ float simn[N_SZ];
    __shared__ float tnv[N_SZ];
    __shared__ float s_tp;
    __shared__ float rm[256], rs[256];

    idxbuf[tid] = indexs[tid];
    // softmax combine for row i (NTILE=256 partials)
    rm[tid] = pmax[i * NTILE + tid];
    rs[tid] = psum[i * NTILE + tid];
    __syncthreads();
    for (int s = 128; s > 0; s >>= 1) {
        if (tid < s) {
            float a = rm[tid], sa = rs[tid];
            float b = rm[tid + s], sb = rs[tid + s];
            float nn = fmaxf(a, b);
            rs[tid] = sa * __expf(a - nn) + sb * __expf(b - nn);
            rm[tid] = nn;
        }
        __syncthreads();
    }

    const float* row = outputs + (size_t)i * C_SZ;
    const float ni_norm = norms[i];

    if (tid == 0) {
        float logZ = rm[0] + logf(rs[0]);
        bu_part[i] = -(row[targets[i]] - logZ);
    }

    // pair matching (indexs is a permutation -> at most one match; argmax = first)
    if (tid < P_SZ) {
        int pp = ppairs[i * P_SZ + tid];
        int f = -1;
        if (pp >= 0) for (int j = 0; j < B_SZ; j++) if (idxbuf[j] == pp) { f = j; break; }
        pj[tid] = f;
    } else if (tid < P_SZ + N_SZ) {
        int t = tid - P_SZ;
        int np = npairs[i * N_SZ + t];
        int f = -1;
        if (np >= 0) for (int j = 0; j < B_SZ; j++) if (idxbuf[j] == np) { f = j; break; }
        nj[t] = f;
        int cid = cluster[np < 0 ? 0 : np];           // jnp.clip(npairs, 0)
        tnv[t] = row[cid] / ni_norm;                  // tsims[i, ncid] = outputs/norm
    }
    if (tid == P_SZ + N_SZ) s_tp = row[targets[i]] / ni_norm;
    __syncthreads();

    // in-batch sims (fp32, exact semantics incl. self-match ~1.0): one pair per wave round-robin
    const int lane = tid & 63, wv = tid >> 6;
    for (int qq = wv; qq < P_SZ + N_SZ; qq += 4) {
        int j = (qq < P_SZ) ? pj[qq] : nj[qq - P_SZ];
        float s = 0.f;
        if (j >= 0) {
            const float* xi = inputs + (size_t)i * F_SZ;
            const float* xj = inputs + (size_t)j * F_SZ;
            float d = 0.f;
            for (int k = lane; k < F_SZ; k += 64) d += xi[k] * xj[k];
            for (int off = 32; off > 0; off >>= 1) d += __shfl_down(d, off);
            s = d / (ni_norm * norms[j]);
        }
        if (lane == 0) { if (qq < P_SZ) simp[qq] = s; else simn[qq - P_SZ] = s; }
    }
    __syncthreads();

    if (tid == 0) {
        float psims[P_SZ + 1]; bool pmask[P_SZ + 1];
        for (int p = 0; p < P_SZ; p++) {
            int pp = ppairs[i * P_SZ + p];
            pmask[p] = (pj[p] >= 0) && (pp >= 0);
            psims[p] = simp[p];
        }
        psims[P_SZ] = s_tp; pmask[P_SZ] = (s_tp != 0.0f);

        float nsims[2 * N_SZ]; bool nmask[2 * N_SZ];
        for (int t = 0; t < N_SZ; t++) {
            int np = npairs[i * N_SZ + t];
            nmask[t] = (nj[t] >= 0) && (np >= 0);
            nsims[t] = simn[t];
            nsims[N_SZ + t] = tnv[t];
            nmask[N_SZ + t] = (np >= 0) && (tnv[t] != 0.0f);
        }
        bool anyp = false, anyn = false;
        float maxn = -INFINITY, minp = INFINITY;
        for (int t = 0; t < 2 * N_SZ; t++) if (nmask[t]) { anyn = true; maxn = fmaxf(maxn, nsims[t]); }
        for (int p = 0; p < P_SZ + 1; p++) if (pmask[p]) { anyp = true; minp = fminf(minp, psims[p]); }
        float p_thrd = (anyn ? maxn : -3.0f) + 0.1f;
        float n_thrd = (anyp ? minp : 3.0f) - 0.1f;
        float hps = 0.f, hns = 0.f; int fl = 0;
        for (int p = 0; p < P_SZ + 1; p++)
            if (pmask[p] && psims[p] < p_thrd) { fl |= 1; hps += expf(-2.0f * (psims[p] - 0.5f)); }
        for (int t = 0; t < 2 * N_SZ; t++)
            if (nmask[t] && nsims[t] > n_thrd && nsims[t] < 0.999999f) { fl |= 2; hns += expf(50.0f * (nsims[t] - 0.5f)); }
        hp_part[i] = hps; hn_part[i] = hns; flag_part[i] = fl;
    }
}

// ---------------- kernel 4: final scalar reduce ----------------
__global__ __launch_bounds__(256) void finalize_kernel(
    const float* __restrict__ bu_part, const float* __restrict__ hp_part,
    const float* __restrict__ hn_part, const int* __restrict__ flag_part,
    float* __restrict__ d_out)
{
    __shared__ float r1[256], r2[256], r3[256];
    __shared__ int rf[256];
    const int tid = threadIdx.x;
    r1[tid] = bu_part[tid]; r2[tid] = hp_part[tid]; r3[tid] = hn_part[tid]; rf[tid] = flag_part[tid];
    __syncthreads();
    for (int s = 128; s > 0; s >>= 1) {
        if (tid < s) { r1[tid] += r1[tid+s]; r2[tid] += r2[tid+s]; r3[tid] += r3[tid+s]; rf[tid] |= rf[tid+s]; }
        __syncthreads();
    }
    if (tid == 0) {
        float bu = r1[0] / (float)B_SZ;
        float hp_loss = (rf[0] & 1) ? 0.5f * log1pf(r2[0]) : 0.0f;
        float hn_loss = (rf[0] & 2) ? (1.0f / 50.0f) * log1pf(r3[0]) : 0.0f;
        d_out[0] = 1.0f * bu + 10.0f * (hp_loss + hn_loss);   // W_BU=1, W_H=10
    }
}

extern "C" void kernel_launch(void* const* d_in, const int* in_sizes, int n_in,
                              void* d_out, int out_size, void* d_ws, size_t ws_size,
                              hipStream_t stream) {
    const float* inputs  = (const float*)d_in[0];
    const int*   targets = (const int*)d_in[1];
    const int*   ppairs  = (const int*)d_in[2];
    const int*   npairs  = (const int*)d_in[3];
    const int*   indexs  = (const int*)d_in[4];
    const int*   cluster = (const int*)d_in[5];
    const float* V       = (const float*)d_in[6];
    float* out = (float*)d_out;           // [0] = loss, [1..] = outputs row-major [B][C]

    char* ws = (char*)d_ws;
    unsigned short* Abf = (unsigned short*)ws;                       // 1 MB
    float* norms   = (float*)(ws + (size_t)B_SZ * F_SZ * 2);
    float* bu_part = norms + B_SZ;
    float* hp_part = bu_part + B_SZ;
    float* hn_part = hp_part + B_SZ;
    int*   flag_part = (int*)(hn_part + B_SZ);
    float* pmax = (float*)(flag_part + B_SZ);                        // 256 KB
    float* psum = pmax + (size_t)B_SZ * NTILE;                       // 256 KB

    prep_kernel<<<B_SZ, 256, 0, stream>>>(inputs, Abf, norms);
    gemm_kernel<<<256, 512, 0, stream>>>(Abf, V, out + 1, pmax, psum);
    pairs_kernel<<<B_SZ, 256, 0, stream>>>(inputs, targets, ppairs, npairs, indexs,
                                           cluster, out + 1, norms, pmax, psum,
                                           bu_part, hp_part, hn_part, flag_part);
    finalize_kernel<<<1, 256, 0, stream>>>(bu_part, hp_part, hn_part, flag_part, out);
}